// Round 5
// baseline (870.268 us; speedup 1.0000x reference)
//
#include <hip/hip_runtime.h>
#include <stdint.h>
#include <stddef.h>

#define B_ 4
#define S_ 2048
#define D_ 2048
#define NH 16
#define NKV 4
#define HD 128
#define QKV_N 3072
#define ROWS (B_*S_)

typedef unsigned short u16;
typedef __attribute__((ext_vector_type(8))) unsigned short u16x8;
typedef __attribute__((ext_vector_type(8))) __bf16 bf16x8;
typedef __attribute__((ext_vector_type(4))) float f32x4;

__device__ __forceinline__ u16 f2bf(float f) {
  unsigned u = __builtin_bit_cast(unsigned, f);
  return (u16)((u + 0x7fffu + ((u >> 16) & 1u)) >> 16);
}
__device__ __forceinline__ u16 f2bf_trunc(float f) {
  return (u16)(__builtin_bit_cast(unsigned, f) >> 16);
}
__device__ __forceinline__ float bf2f(u16 h) {
  return __builtin_bit_cast(float, (unsigned)h << 16);
}
__device__ __forceinline__ f32x4 mfma16(u16x8 a, u16x8 b, f32x4 c) {
  return __builtin_amdgcn_mfma_f32_16x16x32_bf16(
      __builtin_bit_cast(bf16x8, a), __builtin_bit_cast(bf16x8, b), c, 0, 0, 0);
}
__device__ __forceinline__ void gld16(const void* g, void* l) {
  __builtin_amdgcn_global_load_lds(
      (const __attribute__((address_space(1))) void*)g,
      (__attribute__((address_space(3))) void*)l, 16, 0, 0);
}

// ---------- elementwise cast x -> bf16 ----------
__global__ __launch_bounds__(256) void k_cast_x(const float* __restrict__ x, u16* __restrict__ xb) {
  int i = blockIdx.x * 256 + threadIdx.x;
  float4 v = ((const float4*)x)[i];
  union { u16 u[4]; uint2 p; } o;
  o.u[0] = f2bf(v.x); o.u[1] = f2bf(v.y); o.u[2] = f2bf(v.z); o.u[3] = f2bf(v.w);
  ((uint2*)xb)[i] = o.p;
}

// ---------- tiled transpose+cast: w[K][N] fp32 -> wt[N][K(=2048 pitch)] bf16 ----------
__global__ __launch_bounds__(256) void k_wt(const float* __restrict__ w, u16* __restrict__ wt, int K, int N) {
  __shared__ float tile[32][33];
  int kb = blockIdx.y * 32, nb = blockIdx.x * 32;
  int tx = threadIdx.x, ty = threadIdx.y;
#pragma unroll
  for (int j = 0; j < 32; j += 8)
    tile[ty + j][tx] = w[(size_t)(kb + ty + j) * N + nb + tx];
  __syncthreads();
#pragma unroll
  for (int j = 0; j < 32; j += 8)
    wt[(size_t)(nb + ty + j) * K + kb + tx] = f2bf(tile[tx][ty + j]);
}

// ---------- m97-style GEMM: C[M][NT] = A[M][2048] * Bt[NT][2048]^T ----------
template<int NT, bool F32OUT>
__global__ __launch_bounds__(256) void k_gemm(const u16* __restrict__ A, const u16* __restrict__ Bt,
                                              void* __restrict__ C) {
  const int K = 2048;
  __shared__ u16 As[128 * 32];
  __shared__ u16 Bs[128 * 32];
  int mb = blockIdx.y * 128, nb = blockIdx.x * 128;
  int t = threadIdx.x;
  int l = t & 63, lane16 = l & 15, quad = l >> 4;
  int w = t >> 6;
  int wm = (w >> 1) * 64, wn = (w & 1) * 64;
  f32x4 acc[4][4] = {};
  for (int k0 = 0; k0 < K; k0 += 32) {
#pragma unroll
    for (int p = 0; p < 2; ++p) {
      int lin = p * 256 + t;
      int row = lin >> 2, ch = lin & 3;
      gld16(A  + (size_t)(mb + row) * K + k0 + ch * 8, As + (p * 256 + (t & 192)) * 8);
      gld16(Bt + (size_t)(nb + row) * K + k0 + ch * 8, Bs + (p * 256 + (t & 192)) * 8);
    }
    __syncthreads();
    u16x8 af[4], bf[4];
#pragma unroll
    for (int mt = 0; mt < 4; ++mt)
      af[mt] = *(const u16x8*)(As + (wm + mt * 16 + lane16) * 32 + quad * 8);
#pragma unroll
    for (int nt = 0; nt < 4; ++nt)
      bf[nt] = *(const u16x8*)(Bs + (wn + nt * 16 + lane16) * 32 + quad * 8);
#pragma unroll
    for (int mt = 0; mt < 4; ++mt)
#pragma unroll
      for (int nt = 0; nt < 4; ++nt)
        acc[mt][nt] = mfma16(af[mt], bf[nt], acc[mt][nt]);
    __syncthreads();
  }
#pragma unroll
  for (int mt = 0; mt < 4; ++mt)
#pragma unroll
    for (int nt = 0; nt < 4; ++nt)
#pragma unroll
      for (int r = 0; r < 4; ++r) {
        int row = mb + wm + mt * 16 + quad * 4 + r;
        int col = nb + wn + nt * 16 + lane16;
        if constexpr (F32OUT)
          ((float*)C)[(size_t)row * NT + col] = acc[mt][nt][r];
        else
          ((u16*)C)[(size_t)row * NT + col] = f2bf(acc[mt][nt][r]);
      }
}

// ---------- RoPE + scatter; Q pre-scaled by log2(e)/sqrt(HD) ----------
__global__ __launch_bounds__(256) void k_rope(const u16* __restrict__ qkv, const float* __restrict__ fc,
                                              const float* __restrict__ fs, u16* __restrict__ Q,
                                              u16* __restrict__ Kk) {
  const float SC = 0.1275174214f;  // log2(e)/sqrt(128), folded into Q
  int row = blockIdx.x;            // b*S + s
  int b = row >> 11, s = row & 2047;
  int t = threadIdx.x;
#pragma unroll
  for (int j = 0; j < 5; ++j) {
    int p = t + j * 256;           // pair index, 0..1279
    int i = p & 63;
    float c = fc[s * 64 + i], sn = fs[s * 64 + i];
    if (p < 1024) {
      int h = p >> 6;
      unsigned pr = *(const unsigned*)(qkv + (size_t)row * QKV_N + h * 128 + 2 * i);
      float xr = bf2f((u16)(pr & 0xffff)), xi = bf2f((u16)(pr >> 16));
      size_t o = (((size_t)(b * NH + h) * S_) + s) * HD + 2 * i;
      unsigned out = (unsigned)f2bf((xr * c - xi * sn) * SC) |
                     ((unsigned)f2bf((xr * sn + xi * c) * SC) << 16);
      *(unsigned*)(Q + o) = out;
    } else {
      int kh = (p - 1024) >> 6;
      unsigned pr = *(const unsigned*)(qkv + (size_t)row * QKV_N + 2048 + kh * 128 + 2 * i);
      float xr = bf2f((u16)(pr & 0xffff)), xi = bf2f((u16)(pr >> 16));
      size_t o = (((size_t)(b * NKV + kh) * S_) + s) * HD + 2 * i;
      unsigned out = (unsigned)f2bf(xr * c - xi * sn) | ((unsigned)f2bf(xr * sn + xi * c) << 16);
      *(unsigned*)(Kk + o) = out;
    }
  }
}

// ---------- V transpose: coalesced loads -> swizzled LDS -> u32-pair transposed reads ----------
__global__ __launch_bounds__(256) void k_vt(const u16* __restrict__ qkv, u16* __restrict__ Vt) {
  __shared__ u16 tile[64 * 128];       // [s][d], chunk-swizzled: chunk ^= s&15
  int blk = blockIdx.x;                // b*128 + kh*32 + sb
  int sb = blk & 31, kh = (blk >> 5) & 3, b = blk >> 7;
  int t = threadIdx.x;
  int s0 = sb * 64;
#pragma unroll
  for (int i = 0; i < 4; ++i) {
    int lin = i * 256 + t;
    int row = lin >> 4, c = lin & 15;
    u16x8 v = *(const u16x8*)(qkv + (size_t)(b * S_ + s0 + row) * QKV_N + 2560 + kh * HD + c * 8);
    *(u16x8*)(tile + row * 128 + ((c ^ (row & 15)) * 8)) = v;
  }
  __syncthreads();
#pragma unroll
  for (int i = 0; i < 2; ++i) {
    int u = i * 256 + t;
    int p = u >> 3, o = u & 7;         // d = 2p, 2p+1 ; s = o*8 .. o*8+7
    u16 lo[8], hi[8];
#pragma unroll
    for (int j = 0; j < 8; ++j) {
      int s = o * 8 + j;
      int cs = (p >> 2) ^ (s & 15);
      unsigned v = *(const unsigned*)(tile + s * 128 + cs * 8 + (p & 3) * 2);
      lo[j] = (u16)(v & 0xffff); hi[j] = (u16)(v >> 16);
    }
    size_t ob = ((size_t)(b * NKV + kh) * HD + 2 * p) * S_ + s0 + o * 8;
    *(u16x8*)(Vt + ob)      = *(u16x8*)lo;
    *(u16x8*)(Vt + ob + S_) = *(u16x8*)hi;
  }
}

// ---------- flash attention v5: 2 heads/block (GQA share), M=64/wave, single-buffer staging ----------
__global__ __launch_bounds__(256, 2) void k_attn(const u16* __restrict__ Q, const u16* __restrict__ Kg,
                                                 const u16* __restrict__ Vt, u16* __restrict__ O) {
  int bx = blockIdx.x;
  int qb = 15 - (bx >> 5);             // big-work blocks first
  int rest = bx & 31;
  int b = rest >> 3, kh = (rest >> 1) & 3, hp = rest & 1;
  int h0 = kh * 4 + hp * 2;            // this block: heads h0, h0+1 (share kv-head kh)
  int t = threadIdx.x;
  int w = t >> 6, l = t & 63, L = l & 15, quad = l >> 4;
  int q0 = qb * 128 + w * 32;          // wave's 32 query rows (used for both heads)

  __shared__ u16 Ks[64 * 128];         // [key][d], chunk ^= key&7
  __shared__ u16 Vs[128 * 64];         // [d][key], chunk ^= d&7
  __shared__ u16 Ps[4][64 * 64];       // per-wave P: 4 m-tiles x 64 keys, chunk ^= row&7
  u16* Pw = &Ps[w][0];

  const u16* Kh = Kg + ((size_t)(b * NKV + kh) * S_) * HD;
  const u16* Vh = Vt + ((size_t)(b * NKV + kh) * HD) * S_;

  u16x8 ones;                          // bf16 1.0 B-fragment -> row sums in acc[.][8]
#pragma unroll
  for (int i = 0; i < 8; ++i) ones[i] = 0x3F80;

  // Q fragments: hm = head*2 + mtile; rows q0 + (hm&1)*16 + ..., head h0 + (hm>>1)
  u16x8 qf[4][4];
#pragma unroll
  for (int hm = 0; hm < 4; ++hm) {
    const u16* Qh = Q + ((size_t)(b * NH + h0 + (hm >> 1)) * S_) * HD;
#pragma unroll
    for (int kk = 0; kk < 4; ++kk)
      qf[hm][kk] = *(const u16x8*)(Qh + (size_t)(q0 + (hm & 1) * 16 + L) * HD + kk * 32 + quad * 8);
  }

  f32x4 acc[4][9] = {};
  int ktiles = 2 * qb + 2;
#pragma unroll 1
  for (int kt = 0; kt < ktiles; ++kt) {
    int kbase = kt * 64;
    __syncthreads();
    // stage K tile (64 keys x 128 d) and V^T tile (128 d x 64 keys) via async DMA
#pragma unroll
    for (int i = 0; i < 4; ++i) {
      int lin = i * 256 + t, row = lin >> 4, c = lin & 15;
      gld16(Kh + (size_t)(kbase + row) * HD + ((c ^ (row & 7)) * 8),
            Ks + (i * 256 + (t & 192)) * 8);
    }
#pragma unroll
    for (int i = 0; i < 4; ++i) {
      int lin = i * 256 + t, d = lin >> 3, c = lin & 7;
      gld16(Vh + (size_t)d * S_ + kbase + ((c ^ (d & 7)) * 8),
            Vs + (i * 256 + (t & 192)) * 8);
    }
    __syncthreads();
    if (kbase > q0 + 31) continue;     // fully masked for this wave; barriers stay uniform

    bool needMask = (kbase + 63 > q0);
    // S = Q K^T per n-tile; exp2 + mask + truncated P store fused (keeps S transient at 16 regs)
#pragma unroll
    for (int n = 0; n < 4; ++n) {
      f32x4 s[4] = {};
#pragma unroll
      for (int kk = 0; kk < 4; ++kk) {
        int key = n * 16 + L;
        u16x8 kf = *(const u16x8*)(Ks + key * 128 + (((kk * 4 + quad) ^ (L & 7)) * 8));
#pragma unroll
        for (int hm = 0; hm < 4; ++hm)
          s[hm] = mfma16(qf[hm][kk], kf, s[hm]);
      }
#pragma unroll
      for (int hm = 0; hm < 4; ++hm)
#pragma unroll
        for (int r = 0; r < 4; ++r) {
          float e = exp2f(s[hm][r]);
          if (needMask) {
            int key = kbase + n * 16 + L;
            int qrow = q0 + (hm & 1) * 16 + quad * 4 + r;
            e = (key <= qrow) ? e : 0.0f;
          }
          int prow = hm * 16 + quad * 4 + r;
          int chunk = n * 2 + (L >> 3);
          Pw[prow * 64 + ((chunk ^ (prow & 7)) * 8) + (L & 7)] = f2bf_trunc(e);
        }
    }
    // O += P V ; row sums via register ones fragment into acc[.][8] (wave-private P, no barrier)
#pragma unroll
    for (int kc = 0; kc < 2; ++kc) {
      u16x8 pf[4];
#pragma unroll
      for (int hm = 0; hm < 4; ++hm) {
        int prow = hm * 16 + L;
        pf[hm] = *(const u16x8*)(Pw + prow * 64 + (((kc * 4 + quad) ^ (L & 7)) * 8));
      }
#pragma unroll
      for (int nt = 0; nt < 8; ++nt) {
        int d = nt * 16 + L;
        u16x8 vf = *(const u16x8*)(Vs + d * 64 + (((kc * 4 + quad) ^ (L & 7)) * 8));
#pragma unroll
        for (int hm = 0; hm < 4; ++hm)
          acc[hm][nt] = mfma16(pf[hm], vf, acc[hm][nt]);
      }
#pragma unroll
      for (int hm = 0; hm < 4; ++hm)
        acc[hm][8] = mfma16(pf[hm], ones, acc[hm][8]);
    }
  }
  // epilogue: normalize by ones-column sums, write [b][s][head*128+d]
#pragma unroll
  for (int hm = 0; hm < 4; ++hm) {
    int head = h0 + (hm >> 1);
#pragma unroll
    for (int r = 0; r < 4; ++r) {
      float inv = 1.0f / acc[hm][8][r];
      int qrow = q0 + (hm & 1) * 16 + quad * 4 + r;
#pragma unroll
      for (int nt = 0; nt < 8; ++nt) {
        int col = head * HD + nt * 16 + L;
        O[(size_t)(b * S_ + qrow) * D_ + col] = f2bf(acc[hm][nt][r] * inv);
      }
    }
  }
}

extern "C" void kernel_launch(void* const* d_in, const int* in_sizes, int n_in,
                              void* d_out, int out_size, void* d_ws, size_t ws_size,
                              hipStream_t stream) {
  const float* x  = (const float*)d_in[0];
  const float* fc = (const float*)d_in[1];
  const float* fs = (const float*)d_in[2];
  const float* wq = (const float*)d_in[3];
  const float* wk = (const float*)d_in[4];
  const float* wv = (const float*)d_in[5];
  const float* wo = (const float*)d_in[6];
  float* out = (float*)d_out;

  u16* p = (u16*)d_ws;
  u16* xb    = p; p += (size_t)ROWS * D_;
  u16* wqkvT = p; p += (size_t)QKV_N * D_;
  u16* woT   = p; p += (size_t)D_ * D_;
  u16* qkv   = p; p += (size_t)ROWS * QKV_N;
  u16* Qr    = p; p += (size_t)ROWS * (NH * HD);
  u16* Kr    = p; p += (size_t)ROWS * (NKV * HD);
  u16* Vtr   = p; p += (size_t)ROWS * (NKV * HD);
  u16* AO    = p; p += (size_t)ROWS * D_;

  k_cast_x<<<dim3(ROWS * D_ / 1024), dim3(256), 0, stream>>>(x, xb);
  k_wt<<<dim3(64, 64), dim3(32, 8), 0, stream>>>(wq, wqkvT, 2048, 2048);
  k_wt<<<dim3(16, 64), dim3(32, 8), 0, stream>>>(wk, wqkvT + (size_t)2048 * 2048, 2048, 512);
  k_wt<<<dim3(16, 64), dim3(32, 8), 0, stream>>>(wv, wqkvT + (size_t)2560 * 2048, 2048, 512);
  k_wt<<<dim3(64, 64), dim3(32, 8), 0, stream>>>(wo, woT, 2048, 2048);
  k_gemm<QKV_N, false><<<dim3(QKV_N / 128, ROWS / 128), dim3(256), 0, stream>>>(xb, wqkvT, qkv);
  k_rope<<<dim3(ROWS), dim3(256), 0, stream>>>(qkv, fc, fs, Qr, Kr);
  k_vt<<<dim3(B_ * NKV * (S_ / 64)), dim3(256), 0, stream>>>(qkv, Vtr);
  k_attn<<<dim3(512), dim3(256), 0, stream>>>(Qr, Kr, Vtr, AO);
  k_gemm<D_, true><<<dim3(D_ / 128, ROWS / 128), dim3(256), 0, stream>>>(AO, woT, out);
}

// Round 6
// 500.752 us; speedup vs baseline: 1.7379x; 1.7379x over previous
//
#include <hip/hip_runtime.h>
#include <stdint.h>
#include <stddef.h>

#define B_ 4
#define S_ 2048
#define D_ 2048
#define NH 16
#define NKV 4
#define HD 128
#define QKV_N 3072
#define ROWS (B_*S_)

typedef unsigned short u16;
typedef __attribute__((ext_vector_type(8))) unsigned short u16x8;
typedef __attribute__((ext_vector_type(8))) __bf16 bf16x8;
typedef __attribute__((ext_vector_type(4))) float f32x4;

__device__ __forceinline__ u16 f2bf(float f) {
  unsigned u = __builtin_bit_cast(unsigned, f);
  return (u16)((u + 0x7fffu + ((u >> 16) & 1u)) >> 16);
}
__device__ __forceinline__ float bf2f(u16 h) {
  return __builtin_bit_cast(float, (unsigned)h << 16);
}
__device__ __forceinline__ f32x4 mfma16(u16x8 a, u16x8 b, f32x4 c) {
  return __builtin_amdgcn_mfma_f32_16x16x32_bf16(
      __builtin_bit_cast(bf16x8, a), __builtin_bit_cast(bf16x8, b), c, 0, 0, 0);
}
__device__ __forceinline__ void gld16(const void* g, void* l) {
  __builtin_amdgcn_global_load_lds(
      (const __attribute__((address_space(1))) void*)g,
      (__attribute__((address_space(3))) void*)l, 16, 0, 0);
}

// ---------- elementwise cast x -> bf16 ----------
__global__ __launch_bounds__(256) void k_cast_x(const float* __restrict__ x, u16* __restrict__ xb) {
  int i = blockIdx.x * 256 + threadIdx.x;
  float4 v = ((const float4*)x)[i];
  union { u16 u[4]; uint2 p; } o;
  o.u[0] = f2bf(v.x); o.u[1] = f2bf(v.y); o.u[2] = f2bf(v.z); o.u[3] = f2bf(v.w);
  ((uint2*)xb)[i] = o.p;
}

// ---------- tiled transpose+cast: w[K][N] fp32 -> wt[N][K(=2048 pitch)] bf16 ----------
__global__ __launch_bounds__(256) void k_wt(const float* __restrict__ w, u16* __restrict__ wt, int K, int N) {
  __shared__ float tile[32][33];
  int kb = blockIdx.y * 32, nb = blockIdx.x * 32;
  int tx = threadIdx.x, ty = threadIdx.y;
#pragma unroll
  for (int j = 0; j < 32; j += 8)
    tile[ty + j][tx] = w[(size_t)(kb + ty + j) * N + nb + tx];
  __syncthreads();
#pragma unroll
  for (int j = 0; j < 32; j += 8)
    wt[(size_t)(nb + ty + j) * K + kb + tx] = f2bf(tile[tx][ty + j]);
}

// ---------- m97-style GEMM: C[M][NT] = A[M][2048] * Bt[NT][2048]^T ----------
template<int NT, bool F32OUT>
__global__ __launch_bounds__(256) void k_gemm(const u16* __restrict__ A, const u16* __restrict__ Bt,
                                              void* __restrict__ C) {
  const int K = 2048;
  __shared__ u16 As[128 * 32];
  __shared__ u16 Bs[128 * 32];
  int mb = blockIdx.y * 128, nb = blockIdx.x * 128;
  int t = threadIdx.x;
  int l = t & 63, lane16 = l & 15, quad = l >> 4;
  int w = t >> 6;
  int wm = (w >> 1) * 64, wn = (w & 1) * 64;
  f32x4 acc[4][4] = {};
  for (int k0 = 0; k0 < K; k0 += 32) {
#pragma unroll
    for (int p = 0; p < 2; ++p) {
      int lin = p * 256 + t;
      int row = lin >> 2, ch = lin & 3;
      gld16(A  + (size_t)(mb + row) * K + k0 + ch * 8, As + (p * 256 + (t & 192)) * 8);
      gld16(Bt + (size_t)(nb + row) * K + k0 + ch * 8, Bs + (p * 256 + (t & 192)) * 8);
    }
    __syncthreads();
    u16x8 af[4], bf[4];
#pragma unroll
    for (int mt = 0; mt < 4; ++mt)
      af[mt] = *(const u16x8*)(As + (wm + mt * 16 + lane16) * 32 + quad * 8);
#pragma unroll
    for (int nt = 0; nt < 4; ++nt)
      bf[nt] = *(const u16x8*)(Bs + (wn + nt * 16 + lane16) * 32 + quad * 8);
#pragma unroll
    for (int mt = 0; mt < 4; ++mt)
#pragma unroll
      for (int nt = 0; nt < 4; ++nt)
        acc[mt][nt] = mfma16(af[mt], bf[nt], acc[mt][nt]);
    __syncthreads();
  }
#pragma unroll
  for (int mt = 0; mt < 4; ++mt)
#pragma unroll
    for (int nt = 0; nt < 4; ++nt)
#pragma unroll
      for (int r = 0; r < 4; ++r) {
        int row = mb + wm + mt * 16 + quad * 4 + r;
        int col = nb + wn + nt * 16 + lane16;
        if constexpr (F32OUT)
          ((float*)C)[(size_t)row * NT + col] = acc[mt][nt][r];
        else
          ((u16*)C)[(size_t)row * NT + col] = f2bf(acc[mt][nt][r]);
      }
}

// ---------- RoPE + scatter; Q pre-scaled by log2(e)/sqrt(HD) ----------
__global__ __launch_bounds__(256) void k_rope(const u16* __restrict__ qkv, const float* __restrict__ fc,
                                              const float* __restrict__ fs, u16* __restrict__ Q,
                                              u16* __restrict__ Kk) {
  const float SC = 0.1275174214f;  // log2(e)/sqrt(128), folded into Q
  int row = blockIdx.x;            // b*S + s
  int b = row >> 11, s = row & 2047;
  int t = threadIdx.x;
#pragma unroll
  for (int j = 0; j < 5; ++j) {
    int p = t + j * 256;           // pair index, 0..1279
    int i = p & 63;
    float c = fc[s * 64 + i], sn = fs[s * 64 + i];
    if (p < 1024) {
      int h = p >> 6;
      unsigned pr = *(const unsigned*)(qkv + (size_t)row * QKV_N + h * 128 + 2 * i);
      float xr = bf2f((u16)(pr & 0xffff)), xi = bf2f((u16)(pr >> 16));
      size_t o = (((size_t)(b * NH + h) * S_) + s) * HD + 2 * i;
      unsigned out = (unsigned)f2bf((xr * c - xi * sn) * SC) |
                     ((unsigned)f2bf((xr * sn + xi * c) * SC) << 16);
      *(unsigned*)(Q + o) = out;
    } else {
      int kh = (p - 1024) >> 6;
      unsigned pr = *(const unsigned*)(qkv + (size_t)row * QKV_N + 2048 + kh * 128 + 2 * i);
      float xr = bf2f((u16)(pr & 0xffff)), xi = bf2f((u16)(pr >> 16));
      size_t o = (((size_t)(b * NKV + kh) * S_) + s) * HD + 2 * i;
      unsigned out = (unsigned)f2bf(xr * c - xi * sn) | ((unsigned)f2bf(xr * sn + xi * c) << 16);
      *(unsigned*)(Kk + o) = out;
    }
  }
}

// ---------- V transpose: coalesced loads -> swizzled LDS -> u32-pair transposed reads ----------
__global__ __launch_bounds__(256) void k_vt(const u16* __restrict__ qkv, u16* __restrict__ Vt) {
  __shared__ u16 tile[64 * 128];       // [s][d], chunk-swizzled: chunk ^= s&15
  int blk = blockIdx.x;                // b*128 + kh*32 + sb
  int sb = blk & 31, kh = (blk >> 5) & 3, b = blk >> 7;
  int t = threadIdx.x;
  int s0 = sb * 64;
#pragma unroll
  for (int i = 0; i < 4; ++i) {
    int lin = i * 256 + t;
    int row = lin >> 4, c = lin & 15;
    u16x8 v = *(const u16x8*)(qkv + (size_t)(b * S_ + s0 + row) * QKV_N + 2560 + kh * HD + c * 8);
    *(u16x8*)(tile + row * 128 + ((c ^ (row & 15)) * 8)) = v;
  }
  __syncthreads();
#pragma unroll
  for (int i = 0; i < 2; ++i) {
    int u = i * 256 + t;
    int p = u >> 3, o = u & 7;         // d = 2p, 2p+1 ; s = o*8 .. o*8+7
    u16 lo[8], hi[8];
#pragma unroll
    for (int j = 0; j < 8; ++j) {
      int s = o * 8 + j;
      int cs = (p >> 2) ^ (s & 15);
      unsigned v = *(const unsigned*)(tile + s * 128 + cs * 8 + (p & 3) * 2);
      lo[j] = (u16)(v & 0xffff); hi[j] = (u16)(v >> 16);
    }
    size_t ob = ((size_t)(b * NKV + kh) * HD + 2 * p) * S_ + s0 + o * 8;
    *(u16x8*)(Vt + ob)      = *(u16x8*)lo;
    *(u16x8*)(Vt + ob + S_) = *(u16x8*)hi;
  }
}

// ---------- flash attention v6: R2 skeleton + S^T compute (b64 P writes) + hoisted LDS addrs ----------
__global__ __launch_bounds__(256) void k_attn(const u16* __restrict__ Q, const u16* __restrict__ Kg,
                                              const u16* __restrict__ Vt, u16* __restrict__ O) {
  int bx = blockIdx.x;
  int bh = bx >> 3, pr = bx & 7;
  int b = bh >> 4, h = bh & 15, kh = h >> 2;
  int t = threadIdx.x;
  int w = t >> 6, l = t & 63, L = l & 15, quad = l >> 4;

  __shared__ u16 Ks[64 * 128];         // [key][d], chunk ^= key&7
  __shared__ u16 Vs[128 * 64];         // [d][key], chunk ^= d&7
  __shared__ u16 Ps[4][32 * 72];       // per-wave P[q][key], pitch 72
  u16* Pw = &Ps[w][0];

  const u16* Qh = Q  + ((size_t)(b * NH  + h ) * S_) * HD;
  const u16* Kh = Kg + ((size_t)(b * NKV + kh) * S_) * HD;
  const u16* Vh = Vt + ((size_t)(b * NKV + kh) * HD) * S_;

  u16x8 ones;                          // bf16 1.0 B-fragment -> row sums in acc[.][8]
#pragma unroll
  for (int i = 0; i < 8; ++i) ones[i] = 0x3F80;

  // ---- hoisted LDS fragment offsets (u16 units; loop-invariant, imm offsets inside) ----
  int koff[4], voff[2];
#pragma unroll
  for (int kk = 0; kk < 4; ++kk) koff[kk] = 128 * L + 8 * ((4 * kk + quad) ^ (L & 7));
#pragma unroll
  for (int kc = 0; kc < 2; ++kc) voff[kc] = 64 * L + 8 * ((4 * kc + quad) ^ (L & 7));
  const int pread  = 72 * L + 8 * quad;   // + 1152*m + 32*kc (imm)
  const int pwrite = 72 * L + 4 * quad;   // + 1152*m + 16*n  (imm)

  // ---- hoisted staging offsets ----
  int kgo[4], vgo[4], klo[4], vlo[4];
#pragma unroll
  for (int i = 0; i < 4; ++i) {
    int lin = i * 256 + t;
    int row = lin >> 4, c = lin & 15;
    kgo[i] = row * HD + ((c ^ (row & 7)) * 8);
    int d = lin >> 3, c2 = lin & 7;
    vgo[i] = d * S_ + ((c2 ^ (d & 7)) * 8);
    klo[i] = (i * 256 + (t & 192)) * 8;
    vlo[i] = (i * 256 + (t & 192)) * 8;
  }

#pragma unroll 1
  for (int half = 0; half < 2; ++half) {
    int qb = half ? (15 - pr) : pr;
    int q0 = qb * 128 + w * 32;        // this wave's 32 query rows

    u16x8 qf[2][4];
#pragma unroll
    for (int m = 0; m < 2; ++m)
#pragma unroll
      for (int kk = 0; kk < 4; ++kk)
        qf[m][kk] = *(const u16x8*)(Qh + (size_t)(q0 + m * 16 + L) * HD + kk * 32 + quad * 8);

    f32x4 acc[2][9] = {};
    int ktiles = 2 * qb + 2;
#pragma unroll 1
    for (int kt = 0; kt < ktiles; ++kt) {
      int kbase = kt * 64;
      __syncthreads();
      const u16* Kt = Kh + (size_t)kbase * HD;
      const u16* Vg = Vh + kbase;
#pragma unroll
      for (int i = 0; i < 4; ++i) gld16(Kt + kgo[i], Ks + klo[i]);
#pragma unroll
      for (int i = 0; i < 4; ++i) gld16(Vg + vgo[i], Vs + vlo[i]);
      __syncthreads();
      if (kbase > q0 + 31) continue;   // fully masked for this wave; barriers stay uniform

      bool needMask = (kbase + 63 > q0);
      // S^T = K Q^T : A=K-frag, B=Q-frag -> lane holds 4 consecutive keys (rows), col=q
#pragma unroll
      for (int n = 0; n < 4; ++n) {
        f32x4 s0v = {}, s1v = {};
#pragma unroll
        for (int kk = 0; kk < 4; ++kk) {
          u16x8 kf = *(const u16x8*)(Ks + koff[kk] + 2048 * n);
          s0v = mfma16(kf, qf[0][kk], s0v);
          s1v = mfma16(kf, qf[1][kk], s1v);
        }
        // exp2 + mask + packed b64 P store: keys 16n+4quad+r, q = q0+16m+L
#pragma unroll
        for (int m = 0; m < 2; ++m) {
          f32x4 sv = m ? s1v : s0v;
          int qrow = q0 + m * 16 + L;
          unsigned eu[4];
#pragma unroll
          for (int r = 0; r < 4; ++r) {
            float e = exp2f(sv[r]);
            if (needMask) {
              int key = kbase + n * 16 + quad * 4 + r;
              e = (key <= qrow) ? e : 0.0f;
            }
            eu[r] = __builtin_bit_cast(unsigned, e);
          }
          uint2 pk;
          pk.x = __builtin_amdgcn_perm(eu[1], eu[0], 0x07060302u);  // bf16(e0)|bf16(e1)<<16 (trunc)
          pk.y = __builtin_amdgcn_perm(eu[3], eu[2], 0x07060302u);
          *(uint2*)(Pw + pwrite + 1152 * m + 16 * n) = pk;
        }
      }
      // O += P V ; row sums via register ones fragment into acc[.][8] (wave-private P)
#pragma unroll
      for (int kc = 0; kc < 2; ++kc) {
        u16x8 pf0 = *(const u16x8*)(Pw + pread + 32 * kc);
        u16x8 pf1 = *(const u16x8*)(Pw + pread + 1152 + 32 * kc);
#pragma unroll
        for (int nt = 0; nt < 8; ++nt) {
          u16x8 vf = *(const u16x8*)(Vs + voff[kc] + 1024 * nt);
          acc[0][nt] = mfma16(pf0, vf, acc[0][nt]);
          acc[1][nt] = mfma16(pf1, vf, acc[1][nt]);
        }
        acc[0][8] = mfma16(pf0, ones, acc[0][8]);
        acc[1][8] = mfma16(pf1, ones, acc[1][8]);
      }
    }
    // epilogue: normalize by ones-column sums (acc[m][8]), write [b][s][h*128+d]
#pragma unroll
    for (int m = 0; m < 2; ++m)
#pragma unroll
      for (int r = 0; r < 4; ++r) {
        float inv = 1.0f / acc[m][8][r];
        int qrow = q0 + m * 16 + quad * 4 + r;
#pragma unroll
        for (int nt = 0; nt < 8; ++nt) {
          int col = h * HD + nt * 16 + L;
          O[(size_t)(b * S_ + qrow) * D_ + col] = f2bf(acc[m][nt][r] * inv);
        }
      }
  }
}

extern "C" void kernel_launch(void* const* d_in, const int* in_sizes, int n_in,
                              void* d_out, int out_size, void* d_ws, size_t ws_size,
                              hipStream_t stream) {
  const float* x  = (const float*)d_in[0];
  const float* fc = (const float*)d_in[1];
  const float* fs = (const float*)d_in[2];
  const float* wq = (const float*)d_in[3];
  const float* wk = (const float*)d_in[4];
  const float* wv = (const float*)d_in[5];
  const float* wo = (const float*)d_in[6];
  float* out = (float*)d_out;

  u16* p = (u16*)d_ws;
  u16* xb    = p; p += (size_t)ROWS * D_;
  u16* wqkvT = p; p += (size_t)QKV_N * D_;
  u16* woT   = p; p += (size_t)D_ * D_;
  u16* qkv   = p; p += (size_t)ROWS * QKV_N;
  u16* Qr    = p; p += (size_t)ROWS * (NH * HD);
  u16* Kr    = p; p += (size_t)ROWS * (NKV * HD);
  u16* Vtr   = p; p += (size_t)ROWS * (NKV * HD);
  u16* AO    = p; p += (size_t)ROWS * D_;

  k_cast_x<<<dim3(ROWS * D_ / 1024), dim3(256), 0, stream>>>(x, xb);
  k_wt<<<dim3(64, 64), dim3(32, 8), 0, stream>>>(wq, wqkvT, 2048, 2048);
  k_wt<<<dim3(16, 64), dim3(32, 8), 0, stream>>>(wk, wqkvT + (size_t)2048 * 2048, 2048, 512);
  k_wt<<<dim3(16, 64), dim3(32, 8), 0, stream>>>(wv, wqkvT + (size_t)2560 * 2048, 2048, 512);
  k_wt<<<dim3(64, 64), dim3(32, 8), 0, stream>>>(wo, woT, 2048, 2048);
  k_gemm<QKV_N, false><<<dim3(QKV_N / 128, ROWS / 128), dim3(256), 0, stream>>>(xb, wqkvT, qkv);
  k_rope<<<dim3(ROWS), dim3(256), 0, stream>>>(qkv, fc, fs, Qr, Kr);
  k_vt<<<dim3(B_ * NKV * (S_ / 64)), dim3(256), 0, stream>>>(qkv, Vtr);
  k_attn<<<dim3(64 * 8), dim3(256), 0, stream>>>(Qr, Kr, Vtr, AO);
  k_gemm<D_, true><<<dim3(D_ / 128, ROWS / 128), dim3(256), 0, stream>>>(AO, woT, out);
}